// Round 2
// 222.224 us; speedup vs baseline: 1.0562x; 1.0562x over previous
//
#include <hip/hip_runtime.h>
#include <math.h>

// Capsule routing, restructured to avoid materializing u_hat (537 MB).
// o[b,n,:] = W_n * (sum_i c[b,n,i] u[b,i,:]) ;  b[b,n,i] = u[b,i,:] . (W_n^T o_n)
// This round: k_bl + softmax + k_agg fused into k_route (logits never leave LDS).
// Workspace: t(2MB) + sp(16MB) + sp0(0.5MB) = 18.5 MB.
// (Resubmit of round-0 source — round-0 bench died to container infra, no signal.)

#define B   64
#define IN  1024
#define ID  256
#define NC  32
#define DC  64

// ---------------------------------------------------------------------------
// sp0[c][b][d] = sum over i-chunk c of u[b][i][d]   (8 chunks of 128 i)
__global__ __launch_bounds__(256) void k_sumu(const float* __restrict__ u,
                                              float* __restrict__ sp0) {
    const int c = blockIdx.x, b = blockIdx.y;
    const int d = threadIdx.x;
    const float* up = u + ((size_t)b * IN + (size_t)c * (IN / 8)) * ID + d;
    float acc = 0.f;
#pragma unroll 8
    for (int i = 0; i < IN / 8; ++i) acc += up[(size_t)i * ID];
    sp0[(c * B + b) * ID + d] = acc;
}

// ---------------------------------------------------------------------------
// Per (b,n): s = (reduced partials); o = W_n s ; then
//   mode 0: s from sp0 (uniform c=1/32), normalize o, t = W_n^T o_norm
//   mode 1: s from sp,                  normalize o, t = W_n^T o_norm
//   mode 2: s from sp, squash(o) -> out
__global__ __launch_bounds__(256) void k_ot(const float* __restrict__ W,
                                            const float* __restrict__ src,
                                            float* __restrict__ tout,
                                            const int mode) {
    const int bn = blockIdx.x;
    const int b = bn / NC, n = bn % NC;
    __shared__ float s_lds[ID];
    __shared__ float o_lds[DC];
    __shared__ float on_lds[DC];
    const int tid = threadIdx.x;

    // reduce partial sums into s_lds
    float sv = 0.f;
    if (mode == 0) {
#pragma unroll
        for (int c = 0; c < 8; ++c) sv += src[(c * B + b) * ID + tid];
        sv *= (1.0f / NC);
    } else {
#pragma unroll
        for (int c = 0; c < 8; ++c) sv += src[((size_t)(c * B + b) * NC + n) * ID + tid];
    }
    s_lds[tid] = sv;
    __syncthreads();

    // o[d] = dot(W[n*DC+d, :], s)   — wave per row, 16 rows per wave
    const int wave = tid >> 6, lane = tid & 63;
    const float* Wn = W + (size_t)n * DC * ID;
#pragma unroll 4
    for (int r = 0; r < 16; ++r) {
        const int d = wave * 16 + r;
        const float* wrow = Wn + (size_t)d * ID;
        float p = wrow[lane]        * s_lds[lane]
                + wrow[lane + 64]   * s_lds[lane + 64]
                + wrow[lane + 128]  * s_lds[lane + 128]
                + wrow[lane + 192]  * s_lds[lane + 192];
#pragma unroll
        for (int off = 32; off > 0; off >>= 1) p += __shfl_down(p, off);
        if (lane == 0) o_lds[d] = p;
    }
    __syncthreads();

    if (mode == 2) {
        if (tid < DC) {
            float v = o_lds[tid];
            float sq = v * v;
#pragma unroll
            for (int off = 32; off > 0; off >>= 1) sq += __shfl_down(sq, off);
            sq = __shfl(sq, 0) + 1e-7f;
            const float sc = sqrtf(sq) / (0.5f + sq);
            tout[(size_t)(b * NC + n) * DC + tid] = v * sc;
        }
        return;
    }

    // normalize o (F.normalize: x / max(||x||, 1e-12))
    if (tid < DC) {
        float v = o_lds[tid];
        float sq = v * v;
#pragma unroll
        for (int off = 32; off > 0; off >>= 1) sq += __shfl_down(sq, off);
        sq = __shfl(sq, 0);
        const float inv = 1.0f / fmaxf(sqrtf(sq), 1e-12f);
        on_lds[tid] = v * inv;
    }
    __syncthreads();

    // t[k] = sum_d W[n*DC+d, k] * on[d]   — thread per k, coalesced column walk
    float acc = 0.f;
    const float* wc = Wn + tid;
#pragma unroll 8
    for (int d = 0; d < DC; ++d) acc += wc[(size_t)d * ID] * on_lds[d];
    tout[((size_t)b * NC + n) * ID + tid] = acc;
}

// ---------------------------------------------------------------------------
// Fused per-iteration routing step:
//   logits[i][n] = sum_d u[b,i,d] * t[b,n,d]   (in LDS, never to HBM)
//   c = softmax_n(logits)
//   sp[it][b][n][d] = sum_{i in tile} c[i][n] * u[b,i,d]
// Block: one (i-tile of 128, b). LDS 63.7 KB -> 2 blocks/CU.
#define RTILE 128
__global__ __launch_bounds__(256) void k_route(const float* __restrict__ u,
                                               const float* __restrict__ t,
                                               float* __restrict__ sp) {
    const int it = blockIdx.x, b = blockIdx.y;
    const int iBase = it * RTILE;
    __shared__ float Ts[ID][36];      // t[b] transposed: Ts[k][n]  (36.9 KB)
    __shared__ float Us[16][132];     // u chunk transposed: Us[k][i] (8.4 KB)
    __shared__ float cl[RTILE][36];   // logits -> softmax coeffs   (18.4 KB)
    const int tid = threadIdx.x;

    // load full Ts (one-time): thread=k, loop n. Global coalesced.
    {
        const float* tb = t + (size_t)b * NC * ID;
#pragma unroll
        for (int n = 0; n < NC; ++n) Ts[tid][n] = tb[(size_t)n * ID + tid];
    }

    // ---- phase 1: logits (identical MAC structure to old k_bl) ----
    const int q = tid >> 3;   // i-thread: i0 = q*4
    const int r = tid & 7;    // n-thread: n0 = r*4
    float acc[4][4] = {{0.f}};
    const float* ub = u + ((size_t)b * IN + iBase) * ID;

    for (int kc = 0; kc < ID / 16; ++kc) {
        __syncthreads();   // Ts ready (first iter) / prior chunk consumed
        // stage 128 i x 16 k, transposed. 512 float4 loads, 2 per thread.
#pragma unroll
        for (int rep = 0; rep < 2; ++rep) {
            const int f = tid + rep * 256;
            const int i = f >> 2, c4 = f & 3;
            const float4 v = *(const float4*)(ub + (size_t)i * ID + kc * 16 + c4 * 4);
            Us[c4 * 4 + 0][i] = v.x;
            Us[c4 * 4 + 1][i] = v.y;
            Us[c4 * 4 + 2][i] = v.z;
            Us[c4 * 4 + 3][i] = v.w;
        }
        __syncthreads();
#pragma unroll
        for (int k = 0; k < 16; ++k) {
            const float4 a4 = *(const float4*)&Us[k][q * 4];
            const float4 b4 = *(const float4*)&Ts[kc * 16 + k][r * 4];
            const float av[4] = {a4.x, a4.y, a4.z, a4.w};
            const float bv[4] = {b4.x, b4.y, b4.z, b4.w};
#pragma unroll
            for (int ii = 0; ii < 4; ++ii)
#pragma unroll
                for (int jj = 0; jj < 4; ++jj) acc[ii][jj] += av[ii] * bv[jj];
        }
    }

    // logits -> LDS (was: global bl store)
#pragma unroll
    for (int ii = 0; ii < 4; ++ii)
        *(float4*)&cl[q * 4 + ii][r * 4] =
            make_float4(acc[ii][0], acc[ii][1], acc[ii][2], acc[ii][3]);
    __syncthreads();

    // ---- phase 2: softmax over 32 n; 2 threads per i (16 n each) ----
    {
        const int i = tid >> 1, half = tid & 1;
        float v[16];
#pragma unroll
        for (int j = 0; j < 16; ++j) v[j] = cl[i][half * 16 + j];
        float mx = v[0];
#pragma unroll
        for (int j = 1; j < 16; ++j) mx = fmaxf(mx, v[j]);
        mx = fmaxf(mx, __shfl_xor(mx, 1));
        float sum = 0.f;
#pragma unroll
        for (int j = 0; j < 16; ++j) { v[j] = __expf(v[j] - mx); sum += v[j]; }
        sum += __shfl_xor(sum, 1);
        const float inv = 1.0f / sum;
#pragma unroll
        for (int j = 0; j < 16; ++j) cl[i][half * 16 + j] = v[j] * inv;
    }
    __syncthreads();

    // ---- phase 3: weighted aggregation (u tile re-read, L2/LLC-hot) ----
    const int d4 = tid & 63;       // float4 index into ID
    const int ng = tid >> 6;       // n base = ng*8 (wave-uniform -> LDS broadcast)
    float a2[8][4] = {{0.f}};
    const float* ur = ub + d4 * 4;
#pragma unroll 4
    for (int i = 0; i < RTILE; ++i) {
        const float4 uv = *(const float4*)(ur + (size_t)i * ID);
        const float4 c0 = *(const float4*)&cl[i][ng * 8];
        const float4 c1 = *(const float4*)&cl[i][ng * 8 + 4];
        const float cv[8] = {c0.x, c0.y, c0.z, c0.w, c1.x, c1.y, c1.z, c1.w};
        const float uvv[4] = {uv.x, uv.y, uv.z, uv.w};
#pragma unroll
        for (int j = 0; j < 8; ++j)
#pragma unroll
            for (int x = 0; x < 4; ++x) a2[j][x] += cv[j] * uvv[x];
    }

    float* spb = sp + (size_t)(it * B + b) * NC * ID;
#pragma unroll
    for (int j = 0; j < 8; ++j) {
        const int n = ng * 8 + j;
        *(float4*)&spb[(size_t)n * ID + d4 * 4] =
            make_float4(a2[j][0], a2[j][1], a2[j][2], a2[j][3]);
    }
}

// ---------------------------------------------------------------------------
extern "C" void kernel_launch(void* const* d_in, const int* in_sizes, int n_in,
                              void* d_out, int out_size, void* d_ws, size_t ws_size,
                              hipStream_t stream) {
    const float* u = (const float*)d_in[0];   // [B][IN][ID]
    const float* W = (const float*)d_in[1];   // [NC*DC][ID]
    float* out = (float*)d_out;               // [B][NC][DC]

    float* ws  = (float*)d_ws;
    float* t   = ws;                                   // B*NC*ID      = 0.5M floats
    float* sp  = t + (size_t)B * NC * ID;              // 8*B*NC*ID    = 4M floats
    float* sp0 = sp + (size_t)8 * B * NC * ID;         // 8*B*ID       = 128K floats

    const dim3 blk(256);

    // routing iteration 0 (c uniform = 1/32)
    k_sumu <<<dim3(8, B), blk, 0, stream>>>(u, sp0);
    k_ot   <<<dim3(B * NC), blk, 0, stream>>>(W, sp0, t, 0);
    // iteration 1 (logits + softmax + aggregate fused)
    k_route<<<dim3(IN / RTILE, B), blk, 0, stream>>>(u, t, sp);
    k_ot   <<<dim3(B * NC), blk, 0, stream>>>(W, sp, t, 1);
    // iteration 2
    k_route<<<dim3(IN / RTILE, B), blk, 0, stream>>>(u, t, sp);
    k_ot   <<<dim3(B * NC), blk, 0, stream>>>(W, sp, out, 2);
}